// Round 2
// 531.712 us; speedup vs baseline: 1.0788x; 1.0788x over previous
//
#include <hip/hip_runtime.h>
#include <math.h>

#define N_DIM 1000
#define P_DIM 50000
#define Z_DIM 10
#define L_DIM 5
#define NSTEP 50

// precompute grid
#define NTP 256
#define NBP 196          // ceil(50000/256)
#define NSPLIT 4
#define NCHUNK 250       // N_DIM / NSPLIT

// persistent step kernel: plain launch, 49 blocks x 1024 thr = 50176 >= P.
// 49 blocks (16 waves each) on 256 CUs are trivially co-resident; the GPU runs
// one kernel at a time on this stream, so the persistent-spin sync is safe.
#define NT1 1024
#define NBLK 49
#define NEG_BIG (-3.0e38f)
#define SPIN_MAX 32768   // ~10x worst legitimate wait; converts any sync failure
                         // into a wrong-result diagnostic instead of a GPU hang

// ---- workspace layout (floats) ----
constexpr size_t ZP       = (size_t)Z_DIM * P_DIM;          // 500000
constexpr size_t OFF_ZTR  = 0;                              // [Z][P]
constexpr size_t OFF_PART = ZP;                             // u64[NSTEP*64] packed (m,e) partials
constexpr size_t PART_F   = (size_t)NSTEP * 64 * 2;         // in floats (8B per slot)
constexpr size_t OFF_ZZ   = ZP + PART_F;                    // [Z*Z], reserve 128
constexpr size_t WS_ZERO_BYTES = (ZP + PART_F) * sizeof(float);

// ---- output layout (floats) ----
constexpr size_t OUT_MW = 0;
constexpr size_t OUT_VW = (size_t)L_DIM * Z_DIM * P_DIM;    // 2,500,000
constexpr size_t OUT_AL = OUT_VW + (size_t)L_DIM * Z_DIM;   // 2,500,050

// Online-softmax merge of (m,e) pairs. NEG_BIG (not -INF) avoids NaN from inf-inf.
__device__ inline void online_merge(float& m, float& e, float m2, float e2) {
    float M = fmaxf(m, m2);
    e = e * __expf(m - M) + e2 * __expf(m2 - M);
    m = M;
}

// mean_zz[i][j] = sum_n mean_z[n,i]*mean_z[n,j] + N*var_z[i,j]
__global__ __launch_bounds__(256) void init_zz(const float* __restrict__ mean_z,
                                               const float* __restrict__ var_z,
                                               float* __restrict__ ws) {
    float* zz = ws + OFF_ZZ;
    int i = blockIdx.x / Z_DIM, j = blockIdx.x % Z_DIM;
    float s = 0.f;
    for (int n = threadIdx.x; n < N_DIM; n += 256)
        s += mean_z[n * Z_DIM + i] * mean_z[n * Z_DIM + j];
    #pragma unroll
    for (int off = 32; off > 0; off >>= 1) s += __shfl_xor(s, off);
    __shared__ float ls[4];
    if ((threadIdx.x & 63) == 0) ls[threadIdx.x >> 6] = s;
    __syncthreads();
    if (threadIdx.x == 0) {
        float t = ls[0] + ls[1] + ls[2] + ls[3];
        zz[blockIdx.x] = t + (float)N_DIM * var_z[blockIdx.x];
    }
}

// ZtR[z][p] += sum over this block's n-chunk of mean_z[n,z]*data[n,p]  (atomic)
__global__ __launch_bounds__(NTP) void precompute_big(const float* __restrict__ data,
                                                      const float* __restrict__ mean_z,
                                                      float* __restrict__ ws) {
    float* ZtR = ws + OFF_ZTR;
    __shared__ float mzs[NCHUNK * Z_DIM];   // 10 KB
    int n0 = blockIdx.y * NCHUNK;
    for (int i = threadIdx.x; i < NCHUNK * Z_DIM; i += NTP)
        mzs[i] = mean_z[n0 * Z_DIM + i];
    __syncthreads();
    int p = blockIdx.x * NTP + threadIdx.x;
    if (p >= P_DIM) return;

    float acc[Z_DIM];
    #pragma unroll
    for (int z = 0; z < Z_DIM; z++) acc[z] = 0.f;
    for (int r = 0; r < NCHUNK; r++) {
        float d = data[(size_t)(n0 + r) * P_DIM + p];
        #pragma unroll
        for (int z = 0; z < Z_DIM; z++) acc[z] = fmaf(mzs[r * Z_DIM + z], d, acc[z]);
    }
    #pragma unroll
    for (int z = 0; z < Z_DIM; z++) atomicAdd(&ZtR[(size_t)z * P_DIM + p], acc[z]);
}

// All 50 (k,l) steps in one persistent kernel (plain launch).
// Per-p state (W[10], Zt[10], wk, r, logit) lives in registers the whole time;
// the only cross-block traffic per step is one packed 64-bit (m,e) partial per block.
__global__ __launch_bounds__(NT1) void steps_coop(const float* __restrict__ mw0,
                                                  const float* __restrict__ al0,
                                                  const float* __restrict__ pi,
                                                  const float* __restrict__ tau0,
                                                  const float* __restrict__ taup,
                                                  float* __restrict__ ws,
                                                  float* __restrict__ out) {
    const float* ZtR = ws + OFF_ZTR;
    const float* zz  = ws + OFF_ZZ;
    unsigned long long* part = reinterpret_cast<unsigned long long*>(ws + OFF_PART);
    float* out_mw = out + OUT_MW;
    float* out_vw = out + OUT_VW;
    float* out_al = out + OUT_AL;

    __shared__ float sm[NT1 / 64], se[NT1 / 64], bro[2];

    const int tid  = threadIdx.x;
    const int bid  = blockIdx.x;
    const int lane = tid & 63;
    const int wid  = tid >> 6;
    const int p    = bid * NT1 + tid;
    const bool valid = p < P_DIM;
    const float tau = taup[0];

    // ---- load per-p state into registers (static indices only; no scratch) ----
    float W[Z_DIM], Zt[Z_DIM];
    #pragma unroll
    for (int z = 0; z < Z_DIM; z++) { W[z] = 0.f; Zt[z] = 0.f; }
    float mw_c = 0.f, al_c = 0.f, lpi = 0.f;
    if (valid) {
        #pragma unroll
        for (int z = 0; z < Z_DIM; z++) Zt[z] = ZtR[(size_t)z * P_DIM + p];
        #pragma unroll
        for (int z = 0; z < Z_DIM; z++) {
            float w = 0.f;
            #pragma unroll
            for (int l = 0; l < L_DIM; l++) {
                size_t io = ((size_t)l * Z_DIM + z) * P_DIM + p;
                w = fmaf(mw0[io], al0[io], w);          // W0 = sum_l mw*al
            }
            W[z] = w;
        }
        mw_c = mw0[p];                                   // prefetch step 0 (k=0,l=0)
        al_c = al0[p];
        lpi  = __logf(pi[p]);
    }

    float wk = 0.f, r = 0.f;
    int k = 0, l = 0;

    #pragma unroll 1
    for (int s = 0; s < NSTEP; s++) {
        // ---- per-step scalars (uniform) ----
        const float Ezz   = zz[k * Z_DIM + k];
        const float t0v   = tau0[l * Z_DIM + k];
        const float u_var = 1.f / (tau * Ezz + t0v);
        const float s2    = 1.f / (Ezz * tau);
        const float s0inv = 1.f / t0v;
        const float cq    = 0.5f * (tau / Ezz) * (s0inv / (s2 + s0inv));

        if (l == 0) {
            // fresh factor k: r = Zt[k] - sum_{j!=k} zz[k,j]*W[j]; wk = W[k]
            float rr = 0.f, wkk = 0.f;
            #pragma unroll
            for (int j = 0; j < Z_DIM; j++) {
                float zkj = zz[k * Z_DIM + j];
                if (j == k) { rr += Zt[j]; wkk = W[j]; }
                else        { rr = fmaf(-zkj, W[j], rr); }
            }
            r = rr; wk = wkk;
        }

        // ---- compute step (k,l) logits ----
        const size_t io = ((size_t)l * Z_DIM + k) * P_DIM + p;
        float wkl = 0.f, um = 0.f, lgt = NEG_BIG;
        float m = NEG_BIG, e = 0.f;
        if (valid) {
            wkl = wk - mw_c * al_c;
            float E = fmaf(-Ezz, wkl, r);
            um  = tau * u_var * E;
            lgt = fmaf(cq * E, E, lpi);
            out_mw[io] = um;
            m = lgt; e = 1.f;
        }

        // block-level online-softmax reduce (1024 threads = 16 waves)
        #pragma unroll
        for (int off = 32; off > 0; off >>= 1)
            online_merge(m, e, __shfl_xor(m, off), __shfl_xor(e, off));
        if (lane == 0) { sm[wid] = m; se[wid] = e; }
        __syncthreads();                                       // B1
        if (tid == 0) {
            float M = sm[0], E = se[0];
            #pragma unroll
            for (int w = 1; w < NT1 / 64; w++) online_merge(M, E, sm[w], se[w]);
            // pack (m,e): e >= 1 always, so hi-word != 0 is the ready flag.
            unsigned long long v = ((unsigned long long)__float_as_uint(E) << 32)
                                 | (unsigned long long)__float_as_uint(M);
            __hip_atomic_store(&part[(size_t)s * 64 + bid], v, __ATOMIC_RELAXED,
                               __HIP_MEMORY_SCOPE_AGENT);
        }

        // ---- prefetch next step's inputs BEFORE the poll (hides L3 latency) ----
        int kn = k, ln = l + 1;
        if (ln == L_DIM) { ln = 0; kn++; }
        float mw_n = 0.f, al_n = 0.f, lpi_n = lpi;
        if (valid && s + 1 < NSTEP) {
            size_t ion = ((size_t)ln * Z_DIM + kn) * P_DIM + p;
            mw_n = mw0[ion];
            al_n = al0[ion];
            if (ln == 0) lpi_n = __logf(pi[(size_t)kn * P_DIM + p]);
        }

        // ---- single-phase grid sync: wave 0 polls all 49 packed partials ----
        // Bounded spin: on sync failure this exits with garbage (absmax blows up)
        // instead of hanging the GPU — deliberate diagnostic behavior.
        float pm = NEG_BIG, pe = 0.f;
        if (wid == 0) {
            if (lane < NBLK) {
                const unsigned long long* ap = &part[(size_t)s * 64 + lane];
                unsigned long long v = 0;
                for (int it = 0; it < SPIN_MAX; it++) {
                    v = __hip_atomic_load(ap, __ATOMIC_RELAXED, __HIP_MEMORY_SCOPE_AGENT);
                    if ((unsigned)(v >> 32) != 0u) break;
                }
                pm = __uint_as_float((unsigned)v);
                pe = __uint_as_float((unsigned)(v >> 32));
            }
            #pragma unroll
            for (int off = 32; off > 0; off >>= 1)
                online_merge(pm, pe, __shfl_xor(pm, off), __shfl_xor(pe, off));
            if (lane == 0) { bro[0] = pm; bro[1] = pe; }
        }
        __syncthreads();                                       // B2
        const float M    = bro[0];
        const float Sinv = 1.f / bro[1];

        // ---- finalize step (k,l) ----
        if (valid) {
            float a = __expf(lgt - M) * Sinv;
            out_al[io] = a;
            wk = fmaf(um, a, wkl);
        }
        if (p == 0) out_vw[l * Z_DIM + k] = u_var;

        if (l == L_DIM - 1) {
            #pragma unroll
            for (int j = 0; j < Z_DIM; j++) if (j == k) W[j] = wk;  // writeback W[k]
        }
        mw_c = mw_n; al_c = al_n; lpi = lpi_n;
        k = kn; l = ln;
    }
}

extern "C" void kernel_launch(void* const* d_in, const int* in_sizes, int n_in,
                              void* d_out, int out_size, void* d_ws, size_t ws_size,
                              hipStream_t stream) {
    (void)in_sizes; (void)n_in; (void)out_size; (void)ws_size;
    const float* data   = (const float*)d_in[0];
    const float* mean_z = (const float*)d_in[1];
    const float* var_z  = (const float*)d_in[2];
    const float* mw0    = (const float*)d_in[3];
    // d_in[4] var_w: unused (fully overwritten in output)
    const float* al0    = (const float*)d_in[5];
    const float* tau0   = (const float*)d_in[6];
    const float* pi     = (const float*)d_in[7];
    const float* taup   = (const float*)d_in[8];
    float* out = (float*)d_out;
    float* ws  = (float*)d_ws;

    // zero ZtR accumulator + partial slots (ws is poisoned 0xAA before every call;
    // poisoned partials would look "ready", so this memset is correctness-critical)
    hipMemsetAsync(ws, 0, WS_ZERO_BYTES, stream);
    init_zz<<<Z_DIM * Z_DIM, 256, 0, stream>>>(mean_z, var_z, ws);
    precompute_big<<<dim3(NBP, NSPLIT), NTP, 0, stream>>>(data, mean_z, ws);
    steps_coop<<<NBLK, NT1, 0, stream>>>(mw0, al0, pi, tau0, taup, ws, out);
}

// Round 3
// 476.555 us; speedup vs baseline: 1.2037x; 1.1157x over previous
//
#include <hip/hip_runtime.h>
#include <math.h>

#define N_DIM 1000
#define P_DIM 50000
#define Z_DIM 10
#define L_DIM 5
#define NSTEP 50

// precompute grid
#define NTP 256
#define NBP 196          // ceil(50000/256)
#define NSPLIT 4
#define NCHUNK 250       // N_DIM / NSPLIT

// persistent step kernel: plain launch, 49 blocks x 256 thr x 4 p/thread = 50176 >= P.
#define NT1 256
#define PPT 4
#define PBLK (NT1 * PPT) // 1024 p per block
#define NBLK 49
#define NEG_BIG (-3.0e38f)
#define SPIN_MAX 32768   // bounded spin: sync failure -> wrong result, not a hang

// ---- workspace layout (floats) ----
constexpr size_t ZP       = (size_t)Z_DIM * P_DIM;          // 500000
constexpr size_t OFF_ZTR  = 0;                              // [Z][P] (atomic accum, needs zero)
constexpr size_t OFF_PART = ZP;                             // u64[NSTEP*64] packed (m,e) partials (needs zero)
constexpr size_t PART_F   = (size_t)NSTEP * 64 * 2;         // in floats
constexpr size_t OFF_W    = ZP + PART_F;                    // [Z][P] W0 (fully written, no zero)
constexpr size_t OFF_ZZ   = OFF_W + ZP;                     // [Z*Z], reserve 128
constexpr size_t WS_ZERO_BYTES = (ZP + PART_F) * sizeof(float);

// ---- output layout (floats) ----
constexpr size_t OUT_MW = 0;
constexpr size_t OUT_VW = (size_t)L_DIM * Z_DIM * P_DIM;    // 2,500,000
constexpr size_t OUT_AL = OUT_VW + (size_t)L_DIM * Z_DIM;   // 2,500,050

// Online-softmax merge of (m,e) pairs. NEG_BIG (not -INF) avoids NaN from inf-inf.
__device__ inline void online_merge(float& m, float& e, float m2, float e2) {
    float M = fmaxf(m, m2);
    e = e * __expf(m - M) + e2 * __expf(m2 - M);
    m = M;
}

// mean_zz[i][j] = sum_n mean_z[n,i]*mean_z[n,j] + N*var_z[i,j]
__global__ __launch_bounds__(256) void init_zz(const float* __restrict__ mean_z,
                                               const float* __restrict__ var_z,
                                               float* __restrict__ ws) {
    float* zz = ws + OFF_ZZ;
    int i = blockIdx.x / Z_DIM, j = blockIdx.x % Z_DIM;
    float s = 0.f;
    for (int n = threadIdx.x; n < N_DIM; n += 256)
        s += mean_z[n * Z_DIM + i] * mean_z[n * Z_DIM + j];
    #pragma unroll
    for (int off = 32; off > 0; off >>= 1) s += __shfl_xor(s, off);
    __shared__ float ls[4];
    if ((threadIdx.x & 63) == 0) ls[threadIdx.x >> 6] = s;
    __syncthreads();
    if (threadIdx.x == 0) {
        float t = ls[0] + ls[1] + ls[2] + ls[3];
        zz[blockIdx.x] = t + (float)N_DIM * var_z[blockIdx.x];
    }
}

// ZtR[z][p] += chunk of mean_z^T @ data (atomic); W0[z][p] = sum_l mw*al (y==0).
// W0 computed here (full-grid BW) so the 49-CU steps kernel reads 2 MB, not 20 MB.
__global__ __launch_bounds__(NTP) void precompute_big(const float* __restrict__ data,
                                                      const float* __restrict__ mean_z,
                                                      const float* __restrict__ mw0,
                                                      const float* __restrict__ al0,
                                                      float* __restrict__ ws) {
    float* ZtR = ws + OFF_ZTR;
    float* W   = ws + OFF_W;
    __shared__ float mzs[NCHUNK * Z_DIM];   // 10 KB
    int n0 = blockIdx.y * NCHUNK;
    for (int i = threadIdx.x; i < NCHUNK * Z_DIM; i += NTP)
        mzs[i] = mean_z[n0 * Z_DIM + i];
    __syncthreads();
    int p = blockIdx.x * NTP + threadIdx.x;
    if (p >= P_DIM) return;

    float acc[Z_DIM];
    #pragma unroll
    for (int z = 0; z < Z_DIM; z++) acc[z] = 0.f;
    for (int r = 0; r < NCHUNK; r++) {
        float d = data[(size_t)(n0 + r) * P_DIM + p];
        #pragma unroll
        for (int z = 0; z < Z_DIM; z++) acc[z] = fmaf(mzs[r * Z_DIM + z], d, acc[z]);
    }
    #pragma unroll
    for (int z = 0; z < Z_DIM; z++) atomicAdd(&ZtR[(size_t)z * P_DIM + p], acc[z]);

    if (blockIdx.y == 0) {
        #pragma unroll
        for (int z = 0; z < Z_DIM; z++) {
            float w = 0.f;
            #pragma unroll
            for (int l = 0; l < L_DIM; l++) {
                size_t io = ((size_t)l * Z_DIM + z) * P_DIM + p;
                w = fmaf(mw0[io], al0[io], w);
            }
            W[(size_t)z * P_DIM + p] = w;
        }
    }
}

// All 50 (k,l) steps in one persistent kernel (plain launch, 49 blocks co-resident).
// Per-p state (W[10][4], wk, r, saved exps) lives in registers across all steps;
// cross-block traffic per step = one packed 64-bit (m,e) partial per block.
__global__ __launch_bounds__(NT1) void steps_fused(const float* __restrict__ mw0,
                                                   const float* __restrict__ al0,
                                                   const float* __restrict__ pi,
                                                   const float* __restrict__ tau0,
                                                   const float* __restrict__ taup,
                                                   float* __restrict__ ws,
                                                   float* __restrict__ out) {
    const float* ZtR = ws + OFF_ZTR;
    const float* Wg  = ws + OFF_W;
    const float* zz  = ws + OFF_ZZ;
    unsigned long long* part = reinterpret_cast<unsigned long long*>(ws + OFF_PART);
    float* out_mw = out + OUT_MW;
    float* out_vw = out + OUT_VW;
    float* out_al = out + OUT_AL;

    __shared__ float sm[NT1 / 64], se[NT1 / 64], bro[2];

    const int tid  = threadIdx.x;
    const int bid  = blockIdx.x;
    const int lane = tid & 63;
    const int wid  = tid >> 6;
    const int p0   = bid * PBLK + tid * PPT;     // 4 consecutive p; P%4==0 so all-or-none valid
    const bool valid = p0 < P_DIM;
    const float tau = taup[0];

    // ---- per-p register state (all indices compile-time after unroll) ----
    float W[Z_DIM][PPT];
    #pragma unroll
    for (int z = 0; z < Z_DIM; z++)
        #pragma unroll
        for (int i = 0; i < PPT; i++) W[z][i] = 0.f;
    if (valid) {
        #pragma unroll
        for (int z = 0; z < Z_DIM; z++) {
            float4 t = *reinterpret_cast<const float4*>(Wg + (size_t)z * P_DIM + p0);
            W[z][0] = t.x; W[z][1] = t.y; W[z][2] = t.z; W[z][3] = t.w;
        }
    }
    float mw_c[PPT], al_c[PPT], lpi[PPT];
    #pragma unroll
    for (int i = 0; i < PPT; i++) { mw_c[i] = 0.f; al_c[i] = 0.f; lpi[i] = 0.f; }
    if (valid) {                                  // prefetch step 0 (k=0,l=0)
        float4 tm = *reinterpret_cast<const float4*>(mw0 + p0);
        float4 ta = *reinterpret_cast<const float4*>(al0 + p0);
        mw_c[0] = tm.x; mw_c[1] = tm.y; mw_c[2] = tm.z; mw_c[3] = tm.w;
        al_c[0] = ta.x; al_c[1] = ta.y; al_c[2] = ta.z; al_c[3] = ta.w;
        #pragma unroll
        for (int i = 0; i < PPT; i++) lpi[i] = __logf(pi[p0 + i]);
    }

    float wk[PPT], r[PPT];
    #pragma unroll
    for (int i = 0; i < PPT; i++) { wk[i] = 0.f; r[i] = 0.f; }
    int k = 0, l = 0;

    #pragma unroll 1
    for (int s = 0; s < NSTEP; s++) {
        // ---- per-step uniform scalars ----
        const float Ezz   = zz[k * Z_DIM + k];
        const float t0v   = tau0[l * Z_DIM + k];
        const float u_var = 1.f / (tau * Ezz + t0v);
        const float s2    = 1.f / (Ezz * tau);
        const float s0inv = 1.f / t0v;
        const float cq    = 0.5f * (tau / Ezz) * (s0inv / (s2 + s0inv));

        if (l == 0) {
            // fresh factor k: r = ZtR[k] - sum_{j!=k} zz[k,j]*W[j]; wk = W[k]
            float zk[PPT] = {0.f, 0.f, 0.f, 0.f};
            if (valid) {
                float4 t = *reinterpret_cast<const float4*>(ZtR + (size_t)k * P_DIM + p0);
                zk[0] = t.x; zk[1] = t.y; zk[2] = t.z; zk[3] = t.w;
            }
            #pragma unroll
            for (int i = 0; i < PPT; i++) r[i] = zk[i];
            #pragma unroll
            for (int j = 0; j < Z_DIM; j++) {
                float c = (j == k) ? 0.f : zz[k * Z_DIM + j];   // uniform select
                #pragma unroll
                for (int i = 0; i < PPT; i++) r[i] = fmaf(-c, W[j][i], r[i]);
                if (j == k)
                    #pragma unroll
                    for (int i = 0; i < PPT; i++) wk[i] = W[j][i];
            }
        }

        // ---- compute step (k,l) logits ----
        const size_t io = ((size_t)l * Z_DIM + k) * P_DIM + p0;
        float wkl[PPT], um[PPT], lgt[PPT];
        #pragma unroll
        for (int i = 0; i < PPT; i++) { wkl[i] = 0.f; um[i] = 0.f; lgt[i] = NEG_BIG; }
        if (valid) {
            #pragma unroll
            for (int i = 0; i < PPT; i++) {
                wkl[i] = wk[i] - mw_c[i] * al_c[i];
                float E = fmaf(-Ezz, wkl[i], r[i]);
                um[i]  = tau * u_var * E;
                lgt[i] = fmaf(cq * E, E, lpi[i]);
            }
            float4 sv = make_float4(um[0], um[1], um[2], um[3]);
            *reinterpret_cast<float4*>(out_mw + io) = sv;
        }

        // ---- two-pass block softmax: max pass (no exps) ----
        float m4 = fmaxf(fmaxf(lgt[0], lgt[1]), fmaxf(lgt[2], lgt[3]));
        #pragma unroll
        for (int off = 32; off > 0; off >>= 1) m4 = fmaxf(m4, __shfl_xor(m4, off));
        if (lane == 0) sm[wid] = m4;
        __syncthreads();                                       // B1
        const float Mb = fmaxf(fmaxf(sm[0], sm[1]), fmaxf(sm[2], sm[3]));

        // ---- sum pass: 4 exps/thread, saved for the finalize ----
        float esv[PPT];
        #pragma unroll
        for (int i = 0; i < PPT; i++) esv[i] = __expf(lgt[i] - Mb);  // invalid -> exp(NEG_BIG-Mb)=0
        float s4 = (esv[0] + esv[1]) + (esv[2] + esv[3]);
        #pragma unroll
        for (int off = 32; off > 0; off >>= 1) s4 += __shfl_xor(s4, off);
        if (lane == 0) se[wid] = s4;
        __syncthreads();                                       // B2
        if (tid == 0) {
            float Eb = (se[0] + se[1]) + (se[2] + se[3]);      // >= 1: argmax term is exp(0)
            unsigned long long v = ((unsigned long long)__float_as_uint(Eb) << 32)
                                 | (unsigned long long)__float_as_uint(Mb);
            __hip_atomic_store(&part[(size_t)s * 64 + bid], v, __ATOMIC_RELAXED,
                               __HIP_MEMORY_SCOPE_AGENT);
        }

        // ---- prefetch next step's inputs BEFORE the poll (hides L3 latency) ----
        int kn = k, ln = l + 1;
        if (ln == L_DIM) { ln = 0; kn++; }
        float mw_n[PPT], al_n[PPT], lpi_n[PPT];
        #pragma unroll
        for (int i = 0; i < PPT; i++) { mw_n[i] = 0.f; al_n[i] = 0.f; lpi_n[i] = lpi[i]; }
        if (valid && s + 1 < NSTEP) {
            size_t ion = ((size_t)ln * Z_DIM + kn) * P_DIM + p0;
            float4 tm = *reinterpret_cast<const float4*>(mw0 + ion);
            float4 ta = *reinterpret_cast<const float4*>(al0 + ion);
            mw_n[0] = tm.x; mw_n[1] = tm.y; mw_n[2] = tm.z; mw_n[3] = tm.w;
            al_n[0] = ta.x; al_n[1] = ta.y; al_n[2] = ta.z; al_n[3] = ta.w;
            if (ln == 0)
                #pragma unroll
                for (int i = 0; i < PPT; i++) lpi_n[i] = __logf(pi[(size_t)kn * P_DIM + p0 + i]);
        }

        // ---- single-phase grid sync: wave 0 polls the 49 packed partials ----
        float pm = NEG_BIG, pe = 0.f;
        if (wid == 0) {
            if (lane < NBLK) {
                const unsigned long long* ap = &part[(size_t)s * 64 + lane];
                unsigned long long v = 0;
                for (int it = 0; it < SPIN_MAX; it++) {
                    v = __hip_atomic_load(ap, __ATOMIC_RELAXED, __HIP_MEMORY_SCOPE_AGENT);
                    if ((unsigned)(v >> 32) != 0u) break;
                }
                pm = __uint_as_float((unsigned)v);
                pe = __uint_as_float((unsigned)(v >> 32));
            }
            #pragma unroll
            for (int off = 32; off > 0; off >>= 1)
                online_merge(pm, pe, __shfl_xor(pm, off), __shfl_xor(pe, off));
            if (lane == 0) { bro[0] = pm; bro[1] = pe; }
        }
        __syncthreads();                                       // B3
        const float M = bro[0];
        // block-uniform rescale: alpha_i = esv[i] * exp(Mb - M) / S  (1 exp, not 4)
        const float scale = __expf(Mb - M) / bro[1];

        // ---- finalize step (k,l) ----
        if (valid) {
            float a[PPT];
            #pragma unroll
            for (int i = 0; i < PPT; i++) {
                a[i] = esv[i] * scale;
                wk[i] = fmaf(um[i], a[i], wkl[i]);
            }
            float4 sv = make_float4(a[0], a[1], a[2], a[3]);
            *reinterpret_cast<float4*>(out_al + io) = sv;
        }
        if (p0 == 0 && tid == 0) out_vw[l * Z_DIM + k] = u_var;

        if (l == L_DIM - 1) {
            #pragma unroll
            for (int j = 0; j < Z_DIM; j++)
                if (j == k)
                    #pragma unroll
                    for (int i = 0; i < PPT; i++) W[j][i] = wk[i];
        }
        #pragma unroll
        for (int i = 0; i < PPT; i++) { mw_c[i] = mw_n[i]; al_c[i] = al_n[i]; lpi[i] = lpi_n[i]; }
        k = kn; l = ln;
    }
}

extern "C" void kernel_launch(void* const* d_in, const int* in_sizes, int n_in,
                              void* d_out, int out_size, void* d_ws, size_t ws_size,
                              hipStream_t stream) {
    (void)in_sizes; (void)n_in; (void)out_size; (void)ws_size;
    const float* data   = (const float*)d_in[0];
    const float* mean_z = (const float*)d_in[1];
    const float* var_z  = (const float*)d_in[2];
    const float* mw0    = (const float*)d_in[3];
    // d_in[4] var_w: unused (fully overwritten in output)
    const float* al0    = (const float*)d_in[5];
    const float* tau0   = (const float*)d_in[6];
    const float* pi     = (const float*)d_in[7];
    const float* taup   = (const float*)d_in[8];
    float* out = (float*)d_out;
    float* ws  = (float*)d_ws;

    // zero ZtR accumulator + partial slots (ws is poisoned 0xAA before every call;
    // poisoned partials would look "ready", so this memset is correctness-critical)
    hipMemsetAsync(ws, 0, WS_ZERO_BYTES, stream);
    init_zz<<<Z_DIM * Z_DIM, 256, 0, stream>>>(mean_z, var_z, ws);
    precompute_big<<<dim3(NBP, NSPLIT), NTP, 0, stream>>>(data, mean_z, mw0, al0, ws);
    steps_fused<<<NBLK, NT1, 0, stream>>>(mw0, al0, pi, tau0, taup, ws, out);
}